// Round 4
// baseline (627.753 us; speedup 1.0000x reference)
//
#include <hip/hip_runtime.h>
#include <hip/hip_bf16.h>

typedef __bf16 bf16_t;
typedef __bf16 bf16x8 __attribute__((ext_vector_type(8)));
typedef float f32x4 __attribute__((ext_vector_type(4)));

#define GLOAD_LDS16(g, l)                                                      \
  __builtin_amdgcn_global_load_lds(                                            \
      (const __attribute__((address_space(1))) void*)(g),                      \
      (__attribute__((address_space(3))) void*)(l), 16, 0, 0)

#define MFMA(a, b, c) __builtin_amdgcn_mfma_f32_16x16x32_bf16((a), (b), (c), 0, 0, 0)

// ---------------------------------------------------------------------------
// BM=128 x BN=256 tile, BK=32, 8 waves (2M x 4N), wave-tile 64x64.
// acc = 64 VGPR/thread -> with __launch_bounds__(512,4) total regs <=128
// -> 4 waves/SIMD -> 2 blocks/CU (LDS 48KB x2 = 96KB <= 160KB). Cross-block
// overlap hides epilogue + prologue + barrier slop (round-3 deficit).
//
// LDS per buf: A [128][32] 8KB + B [256][32] 16KB = 24KB (12288 elems;
// B at +4096 elems). 16B units XOR-swizzled by ((row>>1)&3) via pre-swizzled
// GLOBAL source (m173); LDS dest stays linear. Measured 0 conflicts (r2).
//
// Phases per K-tile t (quadrants of per-wave 4x4 acc; frag regs af/b0/b1):
//   P0: read A-lo(af) + B-lo(b0) frags; issue stage A(t+1);   MFMA mi01xni01
//       -> vmcnt(1) + barrier   (waits Bg1(t); A(t+1) still flying)
//   P1: read B-hi(b1); issue stage Bg0(t+1);                  MFMA mi01xni23
//   P2: read A-hi(af); issue stage Bg1(t+1);                  MFMA mi23xni23
//   P3: regs only;                                            MFMA mi23xni01
//       -> vmcnt(1) + barrier   (waits A(t+1),Bg0(t+1))
// Per-thread FIFO accounting (1 load per stage call per thread):
//   loop entry t: outstanding {Bg1(t)}<=1; P0 issues A(t+1) -> {Bg1(t),A(t+1)}
//   end-P0 vmcnt(1): Bg1(t) landed (P1 reads it). P1,P2 issue Bg0,Bg1(t+1)
//   end-P3 vmcnt(1): A(t+1),Bg0(t+1) landed (next P0 reads them).  Never 0.
// All ds_reads target buf cur; stages write buf nxt; end-P3 barrier separates
// last read of a buf (P2) from its overwrite (next tile's stages).
//
// u-only LISTA with T = I - S:  u' = soft_thresh(T@u) + Wx
// mode 0: UnextOrWx = bf16(acc)                  (Wx GEMM; u1 = Wx)
// mode 1: UnextOrWx = bf16(soft_thresh(acc) + WxIn)   (no u re-read!)
// mode 2: z = soft_thresh(acc); fused transpose-write Out[b][k][p]
// ---------------------------------------------------------------------------
__global__ __launch_bounds__(512, 4) void gemm_kernel(
    const bf16_t* __restrict__ A, const bf16_t* __restrict__ Bt,
    int Kd, int mode,
    const bf16_t* __restrict__ WxIn, bf16_t* __restrict__ UnextOrWx,
    float* __restrict__ Out, const float* __restrict__ thresh_p)
{
  __shared__ __align__(16) char smem[49152];
  bf16_t* lds = (bf16_t*)smem;

  const int tid = threadIdx.x;
  const int wid = tid >> 6, lane = tid & 63;
  const int wr = wid >> 2, wc = wid & 3;
  const int lr = lane & 15, kg = lane >> 4;

  // XCD-chunked swizzle (grid 1024 % 8 == 0), N-fastest: concurrent blocks
  // on one XCD share A-panels; T/W fully L2-resident.
  const int per = gridDim.x >> 3;
  const int logical = (blockIdx.x & 7) * per + (blockIdx.x >> 3);
  const int tileN = (logical & 3) << 8;
  const int tileM = (logical >> 2) << 7;
  const int NT = Kd >> 5;

  // Thread-invariant staging offsets
  const int l4 = tid & 3, t2 = tid >> 2;
  const int rowA = t2;                                   // 0..127
  const int kcsA = l4 ^ ((rowA >> 1) & 3);
  const size_t offA = (size_t)(tileM + rowA) * Kd + kcsA * 8;

  auto stageA = [&](int t, int buf) {
    GLOAD_LDS16(A + offA + (t << 5), lds + buf * 12288 + tid * 8);
  };
  auto stageB = [&](int t, int g, int buf) {
    const int col = (t2 >> 5) * 64 + g * 32 + (t2 & 31);
    const int kcs = l4 ^ ((col >> 1) & 3);
    GLOAD_LDS16(Bt + (size_t)(tileN + col) * Kd + (t << 5) + kcs * 8,
                lds + buf * 12288 + 4096 + col * 32 + l4 * 8);
  };
  auto readA = [&](int mi, int buf) -> bf16x8 {
    const int R = wr * 64 + mi * 16 + lr;
    return *(const bf16x8*)(lds + buf * 12288 + R * 32 + ((kg ^ ((R >> 1) & 3)) << 3));
  };
  auto readB = [&](int ni, int buf) -> bf16x8 {
    const int C = wc * 64 + ni * 16 + lr;
    return *(const bf16x8*)(lds + buf * 12288 + 4096 + C * 32 + ((kg ^ ((C >> 1) & 3)) << 3));
  };

  f32x4 acc[4][4] = {};
  bf16x8 af[2], b0[2], b1[2];

  // Prologue: tile 0, issue order A, Bg0, Bg1 (FIFO assumed below)
  stageA(0, 0); stageB(0, 0, 0); stageB(0, 1, 0);
  asm volatile("s_waitcnt vmcnt(1)" ::: "memory");   // A(0), Bg0(0) landed
  __builtin_amdgcn_s_barrier();

  for (int t = 0; t < NT; ++t) {
    const int cur = t & 1, nxt = cur ^ 1;
    const int tn = (t + 1 == NT) ? 0 : t + 1;

    // ---- P0
    af[0] = readA(0, cur); af[1] = readA(1, cur);
    b0[0] = readB(0, cur); b0[1] = readB(1, cur);
    stageA(tn, nxt);
    asm volatile("s_waitcnt lgkmcnt(0)" ::: "memory");
    __builtin_amdgcn_sched_barrier(0);
    __builtin_amdgcn_s_setprio(1);
    acc[0][0] = MFMA(af[0], b0[0], acc[0][0]);
    acc[0][1] = MFMA(af[0], b0[1], acc[0][1]);
    acc[1][0] = MFMA(af[1], b0[0], acc[1][0]);
    acc[1][1] = MFMA(af[1], b0[1], acc[1][1]);
    __builtin_amdgcn_s_setprio(0);
    asm volatile("s_waitcnt vmcnt(1)" ::: "memory");   // Bg1(t) landed
    __builtin_amdgcn_s_barrier();

    // ---- P1
    b1[0] = readB(2, cur); b1[1] = readB(3, cur);
    stageB(tn, 0, nxt);
    asm volatile("s_waitcnt lgkmcnt(0)" ::: "memory");
    __builtin_amdgcn_sched_barrier(0);
    __builtin_amdgcn_s_setprio(1);
    acc[0][2] = MFMA(af[0], b1[0], acc[0][2]);
    acc[0][3] = MFMA(af[0], b1[1], acc[0][3]);
    acc[1][2] = MFMA(af[1], b1[0], acc[1][2]);
    acc[1][3] = MFMA(af[1], b1[1], acc[1][3]);
    __builtin_amdgcn_s_setprio(0);

    // ---- P2
    af[0] = readA(2, cur); af[1] = readA(3, cur);
    stageB(tn, 1, nxt);
    asm volatile("s_waitcnt lgkmcnt(0)" ::: "memory");
    __builtin_amdgcn_sched_barrier(0);
    __builtin_amdgcn_s_setprio(1);
    acc[2][2] = MFMA(af[0], b1[0], acc[2][2]);
    acc[2][3] = MFMA(af[0], b1[1], acc[2][3]);
    acc[3][2] = MFMA(af[1], b1[0], acc[3][2]);
    acc[3][3] = MFMA(af[1], b1[1], acc[3][3]);
    __builtin_amdgcn_s_setprio(0);

    // ---- P3 (regs only)
    __builtin_amdgcn_s_setprio(1);
    acc[2][0] = MFMA(af[0], b0[0], acc[2][0]);
    acc[2][1] = MFMA(af[0], b0[1], acc[2][1]);
    acc[3][0] = MFMA(af[1], b0[0], acc[3][0]);
    acc[3][1] = MFMA(af[1], b0[1], acc[3][1]);
    __builtin_amdgcn_s_setprio(0);
    asm volatile("s_waitcnt vmcnt(1)" ::: "memory");   // A(t+1), Bg0(t+1) landed
    __builtin_amdgcn_s_barrier();
  }

  const float th = *thresh_p;

  if (mode == 0) {
    #pragma unroll
    for (int mi = 0; mi < 4; ++mi)
      #pragma unroll
      for (int ni = 0; ni < 4; ++ni) {
        const int row0 = tileM + wr * 64 + mi * 16 + kg * 4;
        const int col  = tileN + wc * 64 + ni * 16 + lr;
        #pragma unroll
        for (int r = 0; r < 4; ++r)
          UnextOrWx[(size_t)(row0 + r) * 1024 + col] = (bf16_t)acc[mi][ni][r];
      }
  } else if (mode == 1) {
    #pragma unroll
    for (int mi = 0; mi < 4; ++mi)
      #pragma unroll
      for (int ni = 0; ni < 4; ++ni) {
        const int row0 = tileM + wr * 64 + mi * 16 + kg * 4;
        const int col  = tileN + wc * 64 + ni * 16 + lr;
        #pragma unroll
        for (int r = 0; r < 4; ++r) {
          const size_t idx = (size_t)(row0 + r) * 1024 + col;
          const float v  = acc[mi][ni][r];
          const float a  = fabsf(v) - th;
          const float zn = (a > 0.f) ? copysignf(a, v) : 0.f;
          UnextOrWx[idx] = (bf16_t)(zn + (float)WxIn[idx]);
        }
      }
  } else {
    // mode 2: z = st(acc), fused transpose via LDS (reused after drain)
    #pragma unroll
    for (int mi = 0; mi < 4; ++mi)
      #pragma unroll
      for (int ni = 0; ni < 4; ++ni)
        #pragma unroll
        for (int r = 0; r < 4; ++r) {
          const float v = acc[mi][ni][r];
          const float a = fabsf(v) - th;
          acc[mi][ni][r] = (a > 0.f) ? copysignf(a, v) : 0.f;
        }
    asm volatile("s_waitcnt vmcnt(0)" ::: "memory");   // stray garbage stages
    __syncthreads();
    float* T = (float*)smem;                           // [32][132] f32
    const int    bb    = tileM >> 10;
    const size_t obase = (size_t)bb * 1048576 + (size_t)(tileM & 1023);
    for (int ch = 0; ch < 8; ++ch) {                   // 32-col chunks
      if (ch) __syncthreads();
      if (wc == (ch >> 1)) {
        #pragma unroll
        for (int nj = 0; nj < 2; ++nj) {
          const int ni = (ch & 1) * 2 + nj;
          const int cp = nj * 16 + lr;
          #pragma unroll
          for (int mi = 0; mi < 4; ++mi)
            #pragma unroll
            for (int r = 0; r < 4; ++r)
              T[cp * 132 + wr * 64 + mi * 16 + kg * 4 + r] = acc[mi][ni][r];
        }
      }
      __syncthreads();
      #pragma unroll
      for (int j = 0; j < 2; ++j) {
        const int f  = tid + j * 512;                  // 0..1023
        const int cp = f >> 5;
        const int R4 = (f & 31) * 4;
        const f32x4 v = *(const f32x4*)&T[cp * 132 + R4];
        *(f32x4*)&Out[obase + (size_t)(tileN + ch * 32 + cp) * 1024 + R4] = v;
      }
    }
  }
}

__global__ void cast_f32_bf16_kernel(const float* __restrict__ src,
                                     bf16_t* __restrict__ dst, int n) {
  int i = blockIdx.x * blockDim.x + threadIdx.x;
  if (i < n) dst[i] = (bf16_t)src[i];
}

// T = I - S, cast to bf16. [1024][1024]
__global__ void make_T_kernel(const float* __restrict__ S,
                              bf16_t* __restrict__ T) {
  const int idx = blockIdx.x * blockDim.x + threadIdx.x;   // 0..1048575
  const int i = idx >> 10, j = idx & 1023;
  T[idx] = (bf16_t)(((i == j) ? 1.0f : 0.0f) - S[idx]);
}

// x [B][C=512][P=1024] f32 -> xt [b*1024+p][c] bf16  (32x32 tiled transpose)
__global__ void transpose_cast_x_kernel(const float* __restrict__ x,
                                        bf16_t* __restrict__ xt) {
  __shared__ float t[32][33];
  const int b  = blockIdx.z;
  const int p0 = blockIdx.x * 32;
  const int c0 = blockIdx.y * 32;
  const int tx = threadIdx.x, ty = threadIdx.y;
  #pragma unroll
  for (int i = 0; i < 32; i += 8)
    t[ty + i][tx] = x[((size_t)b * 512 + c0 + ty + i) * 1024 + p0 + tx];
  __syncthreads();
  #pragma unroll
  for (int i = 0; i < 32; i += 8)
    xt[((size_t)b * 1024 + p0 + ty + i) * 512 + c0 + tx] = (bf16_t)t[tx][ty + i];
}

__global__ void dict_norm_kernel(const float* __restrict__ dict,
                                 float* __restrict__ out) {
  const int row = blockIdx.x;       // 1024
  const int tid = threadIdx.x;      // 256
  const float* r = dict + (size_t)row * 512;
  float s = 0.f;
  for (int i = tid; i < 512; i += 256) { float v = r[i]; s += v * v; }
  #pragma unroll
  for (int off = 32; off > 0; off >>= 1) s += __shfl_down(s, off);
  __shared__ float ps[4];
  if ((tid & 63) == 0) ps[tid >> 6] = s;
  __syncthreads();
  const float inv = 1.0f / sqrtf(ps[0] + ps[1] + ps[2] + ps[3]);
  for (int i = tid; i < 512; i += 256) out[(size_t)row * 512 + i] = r[i] * inv;
}

extern "C" void kernel_launch(void* const* d_in, const int* in_sizes, int n_in,
                              void* d_out, int out_size, void* d_ws, size_t ws_size,
                              hipStream_t stream) {
  const float* x      = (const float*)d_in[0];  // [32,512,32,32]
  const float* dict   = (const float*)d_in[1];  // [1024,512]
  const float* W      = (const float*)d_in[2];  // [1024,512]
  const float* S      = (const float*)d_in[3];  // [1024,1024]
  const float* thresh = (const float*)d_in[4];  // scalar

  float* out = (float*)d_out;

  char* ws = (char*)d_ws;
  bf16_t* uA   = (bf16_t*)ws;                     //  67,108,864 B [32768][1024]
  bf16_t* uB   = (bf16_t*)(ws + 67108864);        //  67,108,864 B
  bf16_t* WxBf = (bf16_t*)(ws + 134217728);       //  67,108,864 B
  bf16_t* xt   = (bf16_t*)(ws + 201326592);       //  33,554,432 B [32768][512]
  bf16_t* Wbf  = (bf16_t*)(ws + 234881024);       //   1,048,576 B
  bf16_t* Tbf  = (bf16_t*)(ws + 235929600);       //   2,097,152 B (end 238,026,752)

  float* dnorm = out + 33554432;                  // dict_norm region (disjoint)

  cast_f32_bf16_kernel<<<dim3(2048), dim3(256), 0, stream>>>(W, Wbf, 524288);
  make_T_kernel<<<dim3(2048), dim3(512), 0, stream>>>(S, Tbf);
  transpose_cast_x_kernel<<<dim3(32, 16, 32), dim3(32, 8), 0, stream>>>(x, xt);
  dict_norm_kernel<<<dim3(1024), dim3(256), 0, stream>>>(dict, dnorm);

  // Wx_t = x_t @ W^T  -> WxBf  (u1 == Wx, read directly by step 1)
  gemm_kernel<<<dim3(1024), dim3(512), 0, stream>>>(
      xt, Wbf, 512, 0, nullptr, WxBf, nullptr, thresh);

  // steps 1..4: u' = soft_thresh(T@u) + Wx
  bf16_t* uc = WxBf; bf16_t* un = uA;
  for (int s = 0; s < 4; ++s) {
    gemm_kernel<<<dim3(1024), dim3(512), 0, stream>>>(
        uc, Tbf, 1024, 1, WxBf, un, nullptr, thresh);
    uc = un;
    un = (uc == uA) ? uB : uA;
  }
  // step 5: z = soft_thresh(T@u), fused transpose to out[b][k][p]
  gemm_kernel<<<dim3(1024), dim3(512), 0, stream>>>(
      uc, Tbf, 1024, 2, nullptr, nullptr, out, thresh);
}

// Round 5
// 591.899 us; speedup vs baseline: 1.0606x; 1.0606x over previous
//
#include <hip/hip_runtime.h>
#include <hip/hip_bf16.h>

typedef __bf16 bf16_t;
typedef __bf16 bf16x8 __attribute__((ext_vector_type(8)));
typedef float f32x4 __attribute__((ext_vector_type(4)));

#define GLOAD_LDS16(g, l)                                                      \
  __builtin_amdgcn_global_load_lds(                                            \
      (const __attribute__((address_space(1))) void*)(g),                      \
      (__attribute__((address_space(3))) void*)(l), 16, 0, 0)

#define MFMA(a, b, c) __builtin_amdgcn_mfma_f32_16x16x32_bf16((a), (b), (c), 0, 0, 0)

// ---------------------------------------------------------------------------
// BM=128 x BN=256, BK=32, 8 waves (2M x 4N), wave-tile 64x64, 2 blocks/CU.
// K-loop identical to round 4 (best profiled: 141us, 0 bank conflicts).
//
// ROUND-5 CHANGE: epilogue write de-amplification. Old epilogue stored bf16
// 2B/lane scattered -> 4 disjoint 32B segments per store instr -> partial-
// line writebacks -> WRITE_SIZE 266MB vs 67MB ideal (4.1x, all rounds).
// New mode-0/1 epilogue repacks acc through LDS f32 [32][260] (pad->2-way
// conflicts only, free per m136), then each thread handles 8 consecutive
// cols of one row: coalesced bf16x8 16B stores (64 lanes = 1KB, full lines)
// + coalesced 16B WxIn loads. Bit-identical arithmetic.
//
// u-only LISTA with T = I - S:  u' = soft_thresh(T@u) + Wx
// mode 0: UnextOrWx = bf16(acc)                       (Wx GEMM; u1 = Wx)
// mode 1: UnextOrWx = bf16(soft_thresh(acc) + WxIn)
// mode 2: z = soft_thresh(acc); fused transpose-write Out[b][k][p] (f32 16B)
// ---------------------------------------------------------------------------
__global__ __launch_bounds__(512, 4) void gemm_kernel(
    const bf16_t* __restrict__ A, const bf16_t* __restrict__ Bt,
    int Kd, int mode,
    const bf16_t* __restrict__ WxIn, bf16_t* __restrict__ UnextOrWx,
    float* __restrict__ Out, const float* __restrict__ thresh_p)
{
  __shared__ __align__(16) char smem[49152];
  bf16_t* lds = (bf16_t*)smem;

  const int tid = threadIdx.x;
  const int wid = tid >> 6, lane = tid & 63;
  const int wr = wid >> 2, wc = wid & 3;
  const int lr = lane & 15, kg = lane >> 4;

  // XCD-chunked swizzle (grid 1024 % 8 == 0), N-fastest.
  const int per = gridDim.x >> 3;
  const int logical = (blockIdx.x & 7) * per + (blockIdx.x >> 3);
  const int tileN = (logical & 3) << 8;
  const int tileM = (logical >> 2) << 7;
  const int NT = Kd >> 5;

  const int l4 = tid & 3, t2 = tid >> 2;
  const int rowA = t2;
  const int kcsA = l4 ^ ((rowA >> 1) & 3);
  const size_t offA = (size_t)(tileM + rowA) * Kd + kcsA * 8;

  auto stageA = [&](int t, int buf) {
    GLOAD_LDS16(A + offA + (t << 5), lds + buf * 12288 + tid * 8);
  };
  auto stageB = [&](int t, int g, int buf) {
    const int col = (t2 >> 5) * 64 + g * 32 + (t2 & 31);
    const int kcs = l4 ^ ((col >> 1) & 3);
    GLOAD_LDS16(Bt + (size_t)(tileN + col) * Kd + (t << 5) + kcs * 8,
                lds + buf * 12288 + 4096 + col * 32 + l4 * 8);
  };
  auto readA = [&](int mi, int buf) -> bf16x8 {
    const int R = wr * 64 + mi * 16 + lr;
    return *(const bf16x8*)(lds + buf * 12288 + R * 32 + ((kg ^ ((R >> 1) & 3)) << 3));
  };
  auto readB = [&](int ni, int buf) -> bf16x8 {
    const int C = wc * 64 + ni * 16 + lr;
    return *(const bf16x8*)(lds + buf * 12288 + 4096 + C * 32 + ((kg ^ ((C >> 1) & 3)) << 3));
  };

  f32x4 acc[4][4] = {};
  bf16x8 af[2], b0[2], b1[2];

  stageA(0, 0); stageB(0, 0, 0); stageB(0, 1, 0);
  asm volatile("s_waitcnt vmcnt(1)" ::: "memory");   // A(0), Bg0(0) landed
  __builtin_amdgcn_s_barrier();

  for (int t = 0; t < NT; ++t) {
    const int cur = t & 1, nxt = cur ^ 1;
    const int tn = (t + 1 == NT) ? 0 : t + 1;

    // ---- P0
    af[0] = readA(0, cur); af[1] = readA(1, cur);
    b0[0] = readB(0, cur); b0[1] = readB(1, cur);
    stageA(tn, nxt);
    asm volatile("s_waitcnt lgkmcnt(0)" ::: "memory");
    __builtin_amdgcn_sched_barrier(0);
    __builtin_amdgcn_s_setprio(1);
    acc[0][0] = MFMA(af[0], b0[0], acc[0][0]);
    acc[0][1] = MFMA(af[0], b0[1], acc[0][1]);
    acc[1][0] = MFMA(af[1], b0[0], acc[1][0]);
    acc[1][1] = MFMA(af[1], b0[1], acc[1][1]);
    __builtin_amdgcn_s_setprio(0);
    asm volatile("s_waitcnt vmcnt(1)" ::: "memory");   // Bg1(t) landed
    __builtin_amdgcn_s_barrier();

    // ---- P1
    b1[0] = readB(2, cur); b1[1] = readB(3, cur);
    stageB(tn, 0, nxt);
    asm volatile("s_waitcnt lgkmcnt(0)" ::: "memory");
    __builtin_amdgcn_sched_barrier(0);
    __builtin_amdgcn_s_setprio(1);
    acc[0][2] = MFMA(af[0], b1[0], acc[0][2]);
    acc[0][3] = MFMA(af[0], b1[1], acc[0][3]);
    acc[1][2] = MFMA(af[1], b1[0], acc[1][2]);
    acc[1][3] = MFMA(af[1], b1[1], acc[1][3]);
    __builtin_amdgcn_s_setprio(0);

    // ---- P2
    af[0] = readA(2, cur); af[1] = readA(3, cur);
    stageB(tn, 1, nxt);
    asm volatile("s_waitcnt lgkmcnt(0)" ::: "memory");
    __builtin_amdgcn_sched_barrier(0);
    __builtin_amdgcn_s_setprio(1);
    acc[2][2] = MFMA(af[0], b1[0], acc[2][2]);
    acc[2][3] = MFMA(af[0], b1[1], acc[2][3]);
    acc[3][2] = MFMA(af[1], b1[0], acc[3][2]);
    acc[3][3] = MFMA(af[1], b1[1], acc[3][3]);
    __builtin_amdgcn_s_setprio(0);

    // ---- P3 (regs only)
    __builtin_amdgcn_s_setprio(1);
    acc[2][0] = MFMA(af[0], b0[0], acc[2][0]);
    acc[2][1] = MFMA(af[0], b0[1], acc[2][1]);
    acc[3][0] = MFMA(af[1], b0[0], acc[3][0]);
    acc[3][1] = MFMA(af[1], b0[1], acc[3][1]);
    __builtin_amdgcn_s_setprio(0);
    asm volatile("s_waitcnt vmcnt(1)" ::: "memory");   // A(t+1), Bg0(t+1) landed
    __builtin_amdgcn_s_barrier();
  }

  const float th = *thresh_p;

  if (mode <= 1) {
    // Repack epilogue: canonical row-major bf16, 16B/lane stores.
    asm volatile("s_waitcnt vmcnt(0)" ::: "memory");   // stray stages landed
    __syncthreads();
    float* Tl = (float*)smem;                          // [32][260] f32, 33280B
    #pragma unroll
    for (int half = 0; half < 2; ++half) {             // wr==half waves own rows
      #pragma unroll
      for (int mc = 0; mc < 2; ++mc) {                 // 32-row chunk
        if (half | mc) __syncthreads();
        if (wr == half) {
          #pragma unroll
          for (int mj = 0; mj < 2; ++mj) {
            const int mi = mc * 2 + mj;
            const int rl = mj * 16 + kg * 4;           // row in 0..31
            #pragma unroll
            for (int ni = 0; ni < 4; ++ni) {
              const int cl = wc * 64 + ni * 16 + lr;
              #pragma unroll
              for (int r = 0; r < 4; ++r)
                Tl[(rl + r) * 260 + cl] = acc[mi][ni][r];
            }
          }
        }
        __syncthreads();
        #pragma unroll
        for (int j = 0; j < 2; ++j) {
          const int chunk = j * 512 + tid;             // 0..1023
          const int rl = chunk >> 5;                   // 0..31
          const int c8 = (chunk & 31) * 8;             // col group
          float v[8];
          *(f32x4*)&v[0] = *(const f32x4*)&Tl[rl * 260 + c8];
          *(f32x4*)&v[4] = *(const f32x4*)&Tl[rl * 260 + c8 + 4];
          const int grow = tileM + half * 64 + mc * 32 + rl;
          const size_t gidx = (size_t)grow * 1024 + tileN + c8;
          bf16x8 ov;
          if (mode == 1) {
            const bf16x8 wx = *(const bf16x8*)&WxIn[gidx];
            #pragma unroll
            for (int e = 0; e < 8; ++e) {
              const float a  = fabsf(v[e]) - th;
              const float zn = (a > 0.f) ? copysignf(a, v[e]) : 0.f;
              ov[e] = (bf16_t)(zn + (float)wx[e]);
            }
          } else {
            #pragma unroll
            for (int e = 0; e < 8; ++e) ov[e] = (bf16_t)v[e];
          }
          *(bf16x8*)&UnextOrWx[gidx] = ov;
        }
      }
    }
  } else {
    // mode 2: z = st(acc), fused transpose via LDS -> Out[b][k][p], f32 16B.
    #pragma unroll
    for (int mi = 0; mi < 4; ++mi)
      #pragma unroll
      for (int ni = 0; ni < 4; ++ni)
        #pragma unroll
        for (int r = 0; r < 4; ++r) {
          const float v = acc[mi][ni][r];
          const float a = fabsf(v) - th;
          acc[mi][ni][r] = (a > 0.f) ? copysignf(a, v) : 0.f;
        }
    asm volatile("s_waitcnt vmcnt(0)" ::: "memory");
    __syncthreads();
    float* T = (float*)smem;                           // [32][132] f32
    const int    bb    = tileM >> 10;
    const size_t obase = (size_t)bb * 1048576 + (size_t)(tileM & 1023);
    for (int ch = 0; ch < 8; ++ch) {                   // 32-col chunks
      if (ch) __syncthreads();
      if (wc == (ch >> 1)) {
        #pragma unroll
        for (int nj = 0; nj < 2; ++nj) {
          const int ni = (ch & 1) * 2 + nj;
          const int cp = nj * 16 + lr;
          #pragma unroll
          for (int mi = 0; mi < 4; ++mi)
            #pragma unroll
            for (int r = 0; r < 4; ++r)
              T[cp * 132 + wr * 64 + mi * 16 + kg * 4 + r] = acc[mi][ni][r];
        }
      }
      __syncthreads();
      #pragma unroll
      for (int j = 0; j < 2; ++j) {
        const int f  = tid + j * 512;                  // 0..1023
        const int cp = f >> 5;
        const int R4 = (f & 31) * 4;
        const f32x4 v = *(const f32x4*)&T[cp * 132 + R4];
        *(f32x4*)&Out[obase + (size_t)(tileN + ch * 32 + cp) * 1024 + R4] = v;
      }
    }
  }
}

__global__ void cast_f32_bf16_kernel(const float* __restrict__ src,
                                     bf16_t* __restrict__ dst, int n) {
  int i = blockIdx.x * blockDim.x + threadIdx.x;
  if (i < n) dst[i] = (bf16_t)src[i];
}

// T = I - S, cast to bf16. [1024][1024]
__global__ void make_T_kernel(const float* __restrict__ S,
                              bf16_t* __restrict__ T) {
  const int idx = blockIdx.x * blockDim.x + threadIdx.x;   // 0..1048575
  const int i = idx >> 10, j = idx & 1023;
  T[idx] = (bf16_t)(((i == j) ? 1.0f : 0.0f) - S[idx]);
}

// x [B][C=512][P=1024] f32 -> xt [b*1024+p][c] bf16  (32x32 tiled transpose)
__global__ void transpose_cast_x_kernel(const float* __restrict__ x,
                                        bf16_t* __restrict__ xt) {
  __shared__ float t[32][33];
  const int b  = blockIdx.z;
  const int p0 = blockIdx.x * 32;
  const int c0 = blockIdx.y * 32;
  const int tx = threadIdx.x, ty = threadIdx.y;
  #pragma unroll
  for (int i = 0; i < 32; i += 8)
    t[ty + i][tx] = x[((size_t)b * 512 + c0 + ty + i) * 1024 + p0 + tx];
  __syncthreads();
  #pragma unroll
  for (int i = 0; i < 32; i += 8)
    xt[((size_t)b * 1024 + p0 + ty + i) * 512 + c0 + tx] = (bf16_t)t[tx][ty + i];
}

__global__ void dict_norm_kernel(const float* __restrict__ dict,
                                 float* __restrict__ out) {
  const int row = blockIdx.x;       // 1024
  const int tid = threadIdx.x;      // 256
  const float* r = dict + (size_t)row * 512;
  float s = 0.f;
  for (int i = tid; i < 512; i += 256) { float v = r[i]; s += v * v; }
  #pragma unroll
  for (int off = 32; off > 0; off >>= 1) s += __shfl_down(s, off);
  __shared__ float ps[4];
  if ((tid & 63) == 0) ps[tid >> 6] = s;
  __syncthreads();
  const float inv = 1.0f / sqrtf(ps[0] + ps[1] + ps[2] + ps[3]);
  for (int i = tid; i < 512; i += 256) out[(size_t)row * 512 + i] = r[i] * inv;
}

extern "C" void kernel_launch(void* const* d_in, const int* in_sizes, int n_in,
                              void* d_out, int out_size, void* d_ws, size_t ws_size,
                              hipStream_t stream) {
  const float* x      = (const float*)d_in[0];  // [32,512,32,32]
  const float* dict   = (const float*)d_in[1];  // [1024,512]
  const float* W      = (const float*)d_in[2];  // [1024,512]
  const float* S      = (const float*)d_in[3];  // [1024,1024]
  const float* thresh = (const float*)d_in[4];  // scalar

  float* out = (float*)d_out;

  char* ws = (char*)d_ws;
  bf16_t* uA   = (bf16_t*)ws;                     //  67,108,864 B [32768][1024]
  bf16_t* uB   = (bf16_t*)(ws + 67108864);        //  67,108,864 B
  bf16_t* WxBf = (bf16_t*)(ws + 134217728);       //  67,108,864 B
  bf16_t* xt   = (bf16_t*)(ws + 201326592);       //  33,554,432 B [32768][512]
  bf16_t* Wbf  = (bf16_t*)(ws + 234881024);       //   1,048,576 B
  bf16_t* Tbf  = (bf16_t*)(ws + 235929600);       //   2,097,152 B (end 238,026,752)

  float* dnorm = out + 33554432;                  // dict_norm region (disjoint)

  cast_f32_bf16_kernel<<<dim3(2048), dim3(256), 0, stream>>>(W, Wbf, 524288);
  make_T_kernel<<<dim3(2048), dim3(512), 0, stream>>>(S, Tbf);
  transpose_cast_x_kernel<<<dim3(32, 16, 32), dim3(32, 8), 0, stream>>>(x, xt);
  dict_norm_kernel<<<dim3(1024), dim3(256), 0, stream>>>(dict, dnorm);

  // Wx_t = x_t @ W^T  -> WxBf  (u1 == Wx, read directly by step 1)
  gemm_kernel<<<dim3(1024), dim3(512), 0, stream>>>(
      xt, Wbf, 512, 0, nullptr, WxBf, nullptr, thresh);

  // steps 1..4: u' = soft_thresh(T@u) + Wx
  bf16_t* uc = WxBf; bf16_t* un = uA;
  for (int s = 0; s < 4; ++s) {
    gemm_kernel<<<dim3(1024), dim3(512), 0, stream>>>(
        uc, Tbf, 1024, 1, WxBf, un, nullptr, thresh);
    uc = un;
    un = (uc == uA) ? uB : uA;
  }
  // step 5: z = soft_thresh(T@u), fused transpose to out[b][k][p]
  gemm_kernel<<<dim3(1024), dim3(512), 0, stream>>>(
      uc, Tbf, 1024, 2, nullptr, nullptr, out, thresh);
}

// Round 6
// 550.128 us; speedup vs baseline: 1.1411x; 1.0759x over previous
//
#include <hip/hip_runtime.h>
#include <hip/hip_bf16.h>

typedef __bf16 bf16_t;
typedef __bf16 bf16x4 __attribute__((ext_vector_type(4)));
typedef __bf16 bf16x8 __attribute__((ext_vector_type(8)));
typedef float f32x4 __attribute__((ext_vector_type(4)));

#define GLOAD_LDS16(g, l)                                                      \
  __builtin_amdgcn_global_load_lds(                                            \
      (const __attribute__((address_space(1))) void*)(g),                      \
      (__attribute__((address_space(3))) void*)(l), 16, 0, 0)

#define MFMA(a, b, c) __builtin_amdgcn_mfma_f32_16x16x32_bf16((a), (b), (c), 0, 0, 0)

// ---------------------------------------------------------------------------
// ROUND 6: deep-pipelined K-loop (m201-style T3+T4), 3-buffer rotation.
// Tile BM=256 x BN=128, BK=64. 512 thr, 8 waves 4Mx2N, wave-tile 64x64
// (acc[4][4] = 64 VGPR -> no round-3 register cliff).
// LDS: 3 bufs x (A[256][64] 32KB + B[128][64] 16KB) = 144KB. Iter t reads
// buf t%3; tiles t+1 (landed-by-read-time) and t+2 (staged this iter) in
// flight => ~2 K-tiles (~8 phases) of latency cover. vmcnt(6) ONCE per
// K-tile (6 = loads/thread/tile => waits tile t+1 landed, t+2 flying).
// Rows are 64 cols = 8 x 16B units; unit XOR-swizzled by (row&7) via
// pre-swizzled GLOBAL source (LDS dest linear, m173); quarter-wave
// ds_read_b128 => 2-way bank alias = free (m136).
// Per K-tile: 2 phases x {8 ds_read_b128; 3 stage loads; barrier;
// lgkmcnt(0); sched_barrier; setprio(1); 16 MFMA; setprio(0)}; then
// vmcnt(6)+barrier. End-of-iter barrier also protects buf reuse
// ((t+3)%3 == t%3): no wave stages into a buffer others still read.
//
// u-only LISTA with T = I - S:  u' = soft_thresh(T@u) + Wx
// mode 0: UnextOrWx = bf16(acc)                       (Wx GEMM; u1 = Wx)
// mode 1: UnextOrWx = bf16(soft_thresh(acc) + WxIn)
// mode 2: z = soft_thresh(acc); fused transpose-write Out[b][k][p]
// ---------------------------------------------------------------------------
__global__ __launch_bounds__(512, 2) void gemm_kernel(
    const bf16_t* __restrict__ A, const bf16_t* __restrict__ Bt,
    int Kd, int mode,
    const bf16_t* __restrict__ WxIn, bf16_t* __restrict__ UnextOrWx,
    float* __restrict__ Out, const float* __restrict__ thresh_p)
{
  __shared__ __align__(16) char smem[147456];
  bf16_t* lds = (bf16_t*)smem;           // buf stride 24576 elems; B at +16384

  const int tid = threadIdx.x;
  const int wid = tid >> 6, lane = tid & 63;
  const int wr = wid >> 1, wc = wid & 1;         // 4M x 2N wave grid
  const int lr = lane & 15, kg = lane >> 4;

  // XCD-chunked swizzle (grid 1024 % 8 == 0), N-fastest: 8 consecutive
  // logical blocks = one M-panel x all 8 N-tiles (share A panel; B=T 2MiB
  // L2-resident).
  const int per = gridDim.x >> 3;
  const int logical = (blockIdx.x & 7) * per + (blockIdx.x >> 3);
  const int tileN = (logical & 7) << 7;          // 0..896
  const int tileM = (logical >> 3) << 8;         // 0..32512
  const int NT = Kd >> 6;

  // Precomputed per-thread staging geometry (A: 4 rounds, B: 2 rounds).
  size_t offA[4]; int dstA[4];
  #pragma unroll
  for (int j = 0; j < 4; ++j) {
    const int f = j * 512 + tid;                 // 0..2047
    const int row = f >> 3, u = f & 7;
    const int ug = u ^ (row & 7);
    offA[j] = (size_t)(tileM + row) * Kd + ug * 8;
    dstA[j] = f * 8;
  }
  size_t offB[2]; int dstB[2];
  #pragma unroll
  for (int j = 0; j < 2; ++j) {
    const int f = j * 512 + tid;                 // 0..1023
    const int col = f >> 3, u = f & 7;
    const int ug = u ^ (col & 7);
    offB[j] = (size_t)(tileN + col) * Kd + ug * 8;
    dstB[j] = 16384 + f * 8;
  }

  auto readA = [&](int mi, int ks, int bs) -> bf16x8 {
    const int R = wr * 64 + mi * 16 + lr;
    const int ul = (ks * 4 + kg) ^ (R & 7);
    return *(const bf16x8*)(lds + bs + R * 64 + ul * 8);
  };
  auto readB = [&](int ni, int ks, int bs) -> bf16x8 {
    const int C = wc * 64 + ni * 16 + lr;
    const int ul = (ks * 4 + kg) ^ (C & 7);
    return *(const bf16x8*)(lds + bs + 16384 + C * 64 + ul * 8);
  };

  f32x4 acc[4][4] = {};
  bf16x8 af[4], bfr[4];

  // Prologue: stage tiles 0 and 1 (6 loads each, A rounds then B rounds).
  #pragma unroll
  for (int j = 0; j < 4; ++j) GLOAD_LDS16(A + offA[j], lds + dstA[j]);
  #pragma unroll
  for (int j = 0; j < 2; ++j) GLOAD_LDS16(Bt + offB[j], lds + dstB[j]);
  if (NT > 1) {
    #pragma unroll
    for (int j = 0; j < 4; ++j) GLOAD_LDS16(A + offA[j] + 64, lds + 24576 + dstA[j]);
    #pragma unroll
    for (int j = 0; j < 2; ++j) GLOAD_LDS16(Bt + offB[j] + 64, lds + 24576 + dstB[j]);
  }
  asm volatile("s_waitcnt vmcnt(6)" ::: "memory");   // tile 0 landed
  __builtin_amdgcn_s_barrier();

  int buf = 0, sb3 = 2;                              // t%3, (t+2)%3
  for (int t = 0; t < NT; ++t) {
    const int bs = buf * 24576;
    const int sbs = sb3 * 24576;
    const int ts = (t + 2 < NT) ? t + 2 : t + 2 - NT;   // wrap refetch (benign)
    const size_t ko = (size_t)ts << 6;

    // ---- Phase A (ks = 0)
    #pragma unroll
    for (int mi = 0; mi < 4; ++mi) af[mi] = readA(mi, 0, bs);
    #pragma unroll
    for (int ni = 0; ni < 4; ++ni) bfr[ni] = readB(ni, 0, bs);
    GLOAD_LDS16(A + offA[0] + ko, lds + sbs + dstA[0]);
    GLOAD_LDS16(A + offA[1] + ko, lds + sbs + dstA[1]);
    GLOAD_LDS16(A + offA[2] + ko, lds + sbs + dstA[2]);
    __builtin_amdgcn_s_barrier();
    asm volatile("s_waitcnt lgkmcnt(0)" ::: "memory");
    __builtin_amdgcn_sched_barrier(0);
    __builtin_amdgcn_s_setprio(1);
    #pragma unroll
    for (int mi = 0; mi < 4; ++mi)
      #pragma unroll
      for (int ni = 0; ni < 4; ++ni)
        acc[mi][ni] = MFMA(af[mi], bfr[ni], acc[mi][ni]);
    __builtin_amdgcn_s_setprio(0);

    // ---- Phase B (ks = 1)
    #pragma unroll
    for (int mi = 0; mi < 4; ++mi) af[mi] = readA(mi, 1, bs);
    #pragma unroll
    for (int ni = 0; ni < 4; ++ni) bfr[ni] = readB(ni, 1, bs);
    GLOAD_LDS16(A + offA[3] + ko, lds + sbs + dstA[3]);
    GLOAD_LDS16(Bt + offB[0] + ko, lds + sbs + dstB[0]);
    GLOAD_LDS16(Bt + offB[1] + ko, lds + sbs + dstB[1]);
    __builtin_amdgcn_s_barrier();
    asm volatile("s_waitcnt lgkmcnt(0)" ::: "memory");
    __builtin_amdgcn_sched_barrier(0);
    __builtin_amdgcn_s_setprio(1);
    #pragma unroll
    for (int mi = 0; mi < 4; ++mi)
      #pragma unroll
      for (int ni = 0; ni < 4; ++ni)
        acc[mi][ni] = MFMA(af[mi], bfr[ni], acc[mi][ni]);
    __builtin_amdgcn_s_setprio(0);
    asm volatile("s_waitcnt vmcnt(6)" ::: "memory");   // tile t+1 landed
    __builtin_amdgcn_s_barrier();

    buf = (buf == 2) ? 0 : buf + 1;
    sb3 = (sb3 == 2) ? 0 : sb3 + 1;
  }

  const float th = *thresh_p;

  if (mode <= 1) {
    // Repack epilogue: canonical row-major bf16, 8B/lane stores (full lines).
    asm volatile("s_waitcnt vmcnt(0)" ::: "memory");   // wrap stages landed
    __syncthreads();
    float* Tl = (float*)smem;                          // [32][132] f32
    #pragma unroll
    for (int c = 0; c < 8; ++c) {                      // 32-row chunks
      if (c) __syncthreads();
      if (wr == (c >> 1)) {
        #pragma unroll
        for (int mj = 0; mj < 2; ++mj) {
          const int mi = (c & 1) * 2 + mj;
          const int rl = mj * 16 + kg * 4;
          #pragma unroll
          for (int ni = 0; ni < 4; ++ni) {
            const int cl = wc * 64 + ni * 16 + lr;
            #pragma unroll
            for (int r = 0; r < 4; ++r)
              Tl[(rl + r) * 132 + cl] = acc[mi][ni][r];
          }
        }
      }
      __syncthreads();
      #pragma unroll
      for (int j = 0; j < 2; ++j) {
        const int f  = j * 512 + tid;                  // 0..1023
        const int rl = f >> 5;                         // 0..31
        const int c4 = (f & 31) * 4;                   // 0..124
        const f32x4 v = *(const f32x4*)&Tl[rl * 132 + c4];
        const int grow = tileM + c * 32 + rl;
        const size_t gidx = (size_t)grow * 1024 + tileN + c4;
        bf16x4 ov;
        if (mode == 1) {
          const bf16x4 wx = *(const bf16x4*)&WxIn[gidx];
          #pragma unroll
          for (int e = 0; e < 4; ++e) {
            const float a  = fabsf(v[e]) - th;
            const float zn = (a > 0.f) ? copysignf(a, v[e]) : 0.f;
            ov[e] = (bf16_t)(zn + (float)wx[e]);
          }
        } else {
          #pragma unroll
          for (int e = 0; e < 4; ++e) ov[e] = (bf16_t)v[e];
        }
        *(bf16x4*)&UnextOrWx[gidx] = ov;
      }
    }
  } else {
    // mode 2: z = st(acc), fused transpose via LDS -> Out[b][k][p], f32 16B.
    #pragma unroll
    for (int mi = 0; mi < 4; ++mi)
      #pragma unroll
      for (int ni = 0; ni < 4; ++ni)
        #pragma unroll
        for (int r = 0; r < 4; ++r) {
          const float v = acc[mi][ni][r];
          const float a = fabsf(v) - th;
          acc[mi][ni][r] = (a > 0.f) ? copysignf(a, v) : 0.f;
        }
    asm volatile("s_waitcnt vmcnt(0)" ::: "memory");
    __syncthreads();
    float* T = (float*)smem;                           // [32][260] f32
    const int    bb    = tileM >> 10;
    const size_t obase = (size_t)bb * 1048576 + (size_t)(tileM & 1023);
    #pragma unroll
    for (int ch = 0; ch < 4; ++ch) {                   // 32-k-col chunks
      if (ch) __syncthreads();
      if (wc == (ch >> 1)) {
        #pragma unroll
        for (int nj = 0; nj < 2; ++nj) {
          const int ni = (ch & 1) * 2 + nj;
          const int cp = nj * 16 + lr;                 // 0..31
          #pragma unroll
          for (int mi = 0; mi < 4; ++mi)
            #pragma unroll
            for (int r = 0; r < 4; ++r)
              T[cp * 260 + wr * 64 + mi * 16 + kg * 4 + r] = acc[mi][ni][r];
        }
      }
      __syncthreads();
      #pragma unroll
      for (int j = 0; j < 4; ++j) {
        const int f  = j * 512 + tid;                  // 0..2047
        const int cp = f >> 6;                         // 0..31
        const int p4 = (f & 63) * 4;                   // 0..252
        const f32x4 v = *(const f32x4*)&T[cp * 260 + p4];
        *(f32x4*)&Out[obase + (size_t)(tileN + ch * 32 + cp) * 1024 + p4] = v;
      }
    }
  }
}

__global__ void cast_f32_bf16_kernel(const float* __restrict__ src,
                                     bf16_t* __restrict__ dst, int n) {
  int i = blockIdx.x * blockDim.x + threadIdx.x;
  if (i < n) dst[i] = (bf16_t)src[i];
}

// T = I - S, cast to bf16. [1024][1024]
__global__ void make_T_kernel(const float* __restrict__ S,
                              bf16_t* __restrict__ T) {
  const int idx = blockIdx.x * blockDim.x + threadIdx.x;   // 0..1048575
  const int i = idx >> 10, j = idx & 1023;
  T[idx] = (bf16_t)(((i == j) ? 1.0f : 0.0f) - S[idx]);
}

// x [B][C=512][P=1024] f32 -> xt [b*1024+p][c] bf16  (32x32 tiled transpose)
__global__ void transpose_cast_x_kernel(const float* __restrict__ x,
                                        bf16_t* __restrict__ xt) {
  __shared__ float t[32][33];
  const int b  = blockIdx.z;
  const int p0 = blockIdx.x * 32;
  const int c0 = blockIdx.y * 32;
  const int tx = threadIdx.x, ty = threadIdx.y;
  #pragma unroll
  for (int i = 0; i < 32; i += 8)
    t[ty + i][tx] = x[((size_t)b * 512 + c0 + ty + i) * 1024 + p0 + tx];
  __syncthreads();
  #pragma unroll
  for (int i = 0; i < 32; i += 8)
    xt[((size_t)b * 1024 + p0 + ty + i) * 512 + c0 + tx] = (bf16_t)t[tx][ty + i];
}

__global__ void dict_norm_kernel(const float* __restrict__ dict,
                                 float* __restrict__ out) {
  const int row = blockIdx.x;       // 1024
  const int tid = threadIdx.x;      // 256
  const float* r = dict + (size_t)row * 512;
  float s = 0.f;
  for (int i = tid; i < 512; i += 256) { float v = r[i]; s += v * v; }
  #pragma unroll
  for (int off = 32; off > 0; off >>= 1) s += __shfl_down(s, off);
  __shared__ float ps[4];
  if ((tid & 63) == 0) ps[tid >> 6] = s;
  __syncthreads();
  const float inv = 1.0f / sqrtf(ps[0] + ps[1] + ps[2] + ps[3]);
  for (int i = tid; i < 512; i += 256) out[(size_t)row * 512 + i] = r[i] * inv;
}

extern "C" void kernel_launch(void* const* d_in, const int* in_sizes, int n_in,
                              void* d_out, int out_size, void* d_ws, size_t ws_size,
                              hipStream_t stream) {
  const float* x      = (const float*)d_in[0];  // [32,512,32,32]
  const float* dict   = (const float*)d_in[1];  // [1024,512]
  const float* W      = (const float*)d_in[2];  // [1024,512]
  const float* S      = (const float*)d_in[3];  // [1024,1024]
  const float* thresh = (const float*)d_in[4];  // scalar

  float* out = (float*)d_out;

  char* ws = (char*)d_ws;
  bf16_t* uA   = (bf16_t*)ws;                     //  67,108,864 B [32768][1024]
  bf16_t* uB   = (bf16_t*)(ws + 67108864);        //  67,108,864 B
  bf16_t* WxBf = (bf16_t*)(ws + 134217728);       //  67,108,864 B
  bf16_t* xt   = (bf16_t*)(ws + 201326592);       //  33,554,432 B [32768][512]
  bf16_t* Wbf  = (bf16_t*)(ws + 234881024);       //   1,048,576 B
  bf16_t* Tbf  = (bf16_t*)(ws + 235929600);       //   2,097,152 B (end 238,026,752)

  float* dnorm = out + 33554432;                  // dict_norm region (disjoint)

  cast_f32_bf16_kernel<<<dim3(2048), dim3(256), 0, stream>>>(W, Wbf, 524288);
  make_T_kernel<<<dim3(2048), dim3(512), 0, stream>>>(S, Tbf);
  transpose_cast_x_kernel<<<dim3(32, 16, 32), dim3(32, 8), 0, stream>>>(x, xt);
  dict_norm_kernel<<<dim3(1024), dim3(256), 0, stream>>>(dict, dnorm);

  // Wx_t = x_t @ W^T  -> WxBf  (u1 == Wx, read directly by step 1)
  gemm_kernel<<<dim3(1024), dim3(512), 0, stream>>>(
      xt, Wbf, 512, 0, nullptr, WxBf, nullptr, thresh);

  // steps 1..4: u' = soft_thresh(T@u) + Wx
  bf16_t* uc = WxBf; bf16_t* un = uA;
  for (int s = 0; s < 4; ++s) {
    gemm_kernel<<<dim3(1024), dim3(512), 0, stream>>>(
        uc, Tbf, 1024, 1, WxBf, un, nullptr, thresh);
    uc = un;
    un = (uc == uA) ? uB : uA;
  }
  // step 5: z = soft_thresh(T@u), fused transpose to out[b][k][p]
  gemm_kernel<<<dim3(1024), dim3(512), 0, stream>>>(
      uc, Tbf, 1024, 2, nullptr, nullptr, out, thresh);
}